// Round 2
// baseline (376.870 us; speedup 1.0000x reference)
//
#include <hip/hip_runtime.h>
#include <stdint.h>

#define CC 256
#define NNq 4096

typedef float f32x4 __attribute__((ext_vector_type(4)));
typedef short bf16x8 __attribute__((ext_vector_type(8)));

#define MFMA16(a, b, c) __builtin_amdgcn_mfma_f32_16x16x32_bf16(a, b, c, 0, 0, 0)

static __device__ __forceinline__ short f2bf(float f) {
  unsigned u = __builtin_bit_cast(unsigned, f);
  u += 0x7fffu + ((u >> 16) & 1u);   // RNE
  return (short)(u >> 16);
}
static __device__ __forceinline__ float bf2f(short s) {
  return __builtin_bit_cast(float, ((unsigned)(unsigned short)s) << 16);
}

// ---------------------------------------------------------------------------
// Kernel 1: projections.
//  - q,k: split hi/lo bf16 in SEPARATE arrays [B][N][32] (direct MFMA frags,
//    zero unpack VALU in consumers); q pre-scaled by log2(e).
//  - v: bf16, layout [B][C][N].
// ---------------------------------------------------------------------------
#define XSTR 66

__global__ __launch_bounds__(256) void proj_kernel(
    const float* __restrict__ x,
    const float* __restrict__ Wq, const float* __restrict__ bq,
    const float* __restrict__ Wk, const float* __restrict__ bk,
    const float* __restrict__ Wv, const float* __restrict__ bv,
    unsigned short* __restrict__ qh_, unsigned short* __restrict__ ql_,
    unsigned short* __restrict__ kh_, unsigned short* __restrict__ kl_,
    unsigned short* __restrict__ vbf)
{
  __shared__ float xs[256 * XSTR];
  const int t = threadIdx.x;
  const int b = blockIdx.x >> 6;
  const int n0 = (blockIdx.x & 63) << 6;
  const float L2E = 1.4426950408889634f;

  const float* xb = x + ((size_t)b * CC) * NNq + n0;
#pragma unroll
  for (int i = 0; i < 16; ++i) {
    int fi = i * 256 + t;
    int c = fi >> 4, nv = (fi & 15) << 2;
    float4 v4 = *(const float4*)(xb + (size_t)c * NNq + nv);
    float* d = &xs[c * XSTR + nv];
    d[0] = v4.x; d[1] = v4.y; d[2] = v4.z; d[3] = v4.w;
  }
  __syncthreads();

  const int w = t >> 6, l = t & 63;
  const int l15 = l & 15, l4 = l >> 4;

  // 20 row-tiles: 16 v + 2 q + 2 k ; wave w owns tiles w*5 .. w*5+4
  f32x4 acc[5][4];
#pragma unroll
  for (int r5 = 0; r5 < 5; ++r5) {
    int rt = w * 5 + r5;
    const float* bias; float bscale;
    if (rt < 16)      { bias = bv + rt * 16;        bscale = 1.f; }
    else if (rt < 18) { bias = bq + (rt - 16) * 16; bscale = L2E; }
    else              { bias = bk + (rt - 18) * 16; bscale = 1.f; }
#pragma unroll
    for (int j = 0; j < 4; ++j) {
      float bval = bias[l4 * 4 + j] * bscale;
#pragma unroll
      for (int nt = 0; nt < 4; ++nt) acc[r5][nt][j] = bval;
    }
  }

#pragma unroll 1
  for (int ks = 0; ks < 8; ++ks) {
    bf16x8 ah[5], al[5];
#pragma unroll
    for (int r5 = 0; r5 < 5; ++r5) {
      int rt = w * 5 + r5;
      const float* wrow; float wscale;
      if (rt < 16)      { wrow = Wv + (size_t)(rt * 16 + l15) * 256;        wscale = 1.f; }
      else if (rt < 18) { wrow = Wq + (size_t)((rt - 16) * 16 + l15) * 256; wscale = L2E; }
      else              { wrow = Wk + (size_t)((rt - 18) * 16 + l15) * 256; wscale = 1.f; }
      const float* src = wrow + ks * 32 + l4 * 8;
#pragma unroll
      for (int i = 0; i < 8; ++i) {
        float v = src[i] * wscale;
        short hh = f2bf(v);
        ah[r5][i] = hh;
        al[r5][i] = f2bf(v - bf2f(hh));
      }
    }
#pragma unroll
    for (int nt = 0; nt < 4; ++nt) {
      bf16x8 bh, bl;
#pragma unroll
      for (int i = 0; i < 8; ++i) {
        float v = xs[(ks * 32 + l4 * 8 + i) * XSTR + nt * 16 + l15];
        short hh = f2bf(v);
        bh[i] = hh;
        bl[i] = f2bf(v - bf2f(hh));
      }
#pragma unroll
      for (int r5 = 0; r5 < 5; ++r5) {
        acc[r5][nt] = MFMA16(ah[r5], bl, acc[r5][nt]);
        acc[r5][nt] = MFMA16(al[r5], bh, acc[r5][nt]);
        acc[r5][nt] = MFMA16(ah[r5], bh, acc[r5][nt]);
      }
    }
  }

#pragma unroll
  for (int r5 = 0; r5 < 5; ++r5) {
    int rt = w * 5 + r5;
#pragma unroll
    for (int nt = 0; nt < 4; ++nt) {
      int n = n0 + nt * 16 + l15;
#pragma unroll
      for (int j = 0; j < 4; ++j) {
        float v = acc[r5][nt][j];
        int sub = l4 * 4 + j;
        if (rt < 16) {
          int c = rt * 16 + sub;
          vbf[((size_t)b * CC + c) * NNq + n] = (unsigned short)f2bf(v);
        } else {
          short hh = f2bf(v);
          short lo = f2bf(v - bf2f(hh));
          unsigned short* dh = (rt < 18) ? qh_ : kh_;
          unsigned short* dl = (rt < 18) ? ql_ : kl_;
          int d = ((rt < 18) ? (rt - 16) : (rt - 18)) * 16 + sub;
          size_t o = ((size_t)b * NNq + n) * 32 + d;
          dh[o] = (unsigned short)hh;
          dl[o] = (unsigned short)lo;
        }
      }
    }
  }
}

// ---------------------------------------------------------------------------
// Kernel 2: softmax row-sums, m-split 8-way. 8192 independent waves.
// Fixed shift 64 (|e| bounded well below): sum = sum exp2(e - 64).
// ---------------------------------------------------------------------------
__global__ __launch_bounds__(256, 8) void stats_kernel(
    const unsigned short* __restrict__ qh_, const unsigned short* __restrict__ ql_,
    const unsigned short* __restrict__ kh_, const unsigned short* __restrict__ kl_,
    float* __restrict__ ps)
{
  const int t = threadIdx.x, w = t >> 6, l = t & 63;
  const int l15 = l & 15, l4 = l >> 4;
  const int wl = blockIdx.x * 4 + w;
  const int split = wl & 7, tg = wl >> 3;     // tg = b*256 + tile
  const int b = tg >> 8, tile = tg & 255;

  const size_t qbase = ((size_t)b * NNq + tile * 16 + l15) * 32 + l4 * 8;
  bf16x8 qh = *(const bf16x8*)(qh_ + qbase);
  bf16x8 qlo = *(const bf16x8*)(ql_ + qbase);
  const unsigned short* khb = kh_ + (size_t)b * NNq * 32;
  const unsigned short* klb = kl_ + (size_t)b * NNq * 32;
  const int m0 = split * 512;

  float sx[4] = {0.f, 0.f, 0.f, 0.f};
#pragma unroll 1
  for (int it = 0; it < 16; ++it) {
    int mb = m0 + it * 32;
#pragma unroll
    for (int hh = 0; hh < 2; ++hh) {
      size_t ko = (size_t)(mb + hh * 16 + l15) * 32 + l4 * 8;
      bf16x8 khf = *(const bf16x8*)(khb + ko);
      bf16x8 klf = *(const bf16x8*)(klb + ko);
      f32x4 e = {0.f, 0.f, 0.f, 0.f};
      e = MFMA16(qh, klf, e);
      e = MFMA16(qlo, khf, e);
      e = MFMA16(qh, khf, e);
#pragma unroll
      for (int j = 0; j < 4; ++j) sx[j] += exp2f(e[j] - 64.0f);
    }
  }
#pragma unroll
  for (int mask = 1; mask < 16; mask <<= 1)
#pragma unroll
    for (int j = 0; j < 4; ++j) sx[j] += __shfl_xor(sx[j], mask);

  if (l15 == 0) {
    float* dst = ps + ((size_t)tg * 8 + split) * 16;
#pragma unroll
    for (int j = 0; j < 4; ++j) dst[l4 * 4 + j] = sx[j];
  }
}

// Merge partial sums -> Crow = 64 + log2(S) per row.
__global__ __launch_bounds__(256) void merge_kernel(
    const float* __restrict__ ps, float* __restrict__ Crow)
{
  int r = blockIdx.x * 256 + threadIdx.x;   // 16384 rows
  int tg = r >> 4, rl = r & 15;
  float S = 0.f;
#pragma unroll
  for (int s = 0; s < 8; ++s) S += ps[((size_t)tg * 8 + s) * 16 + rl];
  Crow[r] = 64.0f + log2f(S);
}

// ---------------------------------------------------------------------------
// Kernel 3: attention write + partial PV. Wave-independent (no barriers).
// Wave = (b, 16-row tile, 1/4 of m). Per-wave 4KB swizzled f32 LDS buffer:
// p staged for (a) coalesced 256B dwordx4 attention stores, (b) PV B-frags.
// ---------------------------------------------------------------------------
static __device__ __forceinline__ int swzb(int row, int bytecol) {
  return row * 256 + (bytecol ^ ((row & 7) << 4));
}

__global__ __launch_bounds__(256, 3) void attn_pv_kernel(
    const unsigned short* __restrict__ qh_, const unsigned short* __restrict__ ql_,
    const unsigned short* __restrict__ kh_, const unsigned short* __restrict__ kl_,
    const unsigned short* __restrict__ vbf, const float* __restrict__ Crow,
    float* __restrict__ out, float* __restrict__ part)
{
  __shared__ float pbuf_f[4][1024];   // per-wave 4KB: [16 rows][64 m] f32, swizzled
  const int t = threadIdx.x, w = t >> 6, l = t & 63;
  const int l15 = l & 15, l4 = l >> 4;
  // XCD swizzle (1024 blocks, 1024%8==0 -> bijective): same b stays on one XCD pair
  const int sb = ((blockIdx.x & 7) << 7) | (blockIdx.x >> 3);
  const int s2 = w;              // m-split 0..3
  const int tg = sb;             // b*256 + tile
  const int b = tg >> 8, tile = tg & 255;
  char* pb = (char*)pbuf_f[w];

  const size_t qbase = ((size_t)b * NNq + tile * 16 + l15) * 32 + l4 * 8;
  bf16x8 qh = *(const bf16x8*)(qh_ + qbase);
  bf16x8 qlo = *(const bf16x8*)(ql_ + qbase);
  f32x4 crow = *(const f32x4*)(Crow + tg * 16 + l4 * 4);
  const unsigned short* khb = kh_ + (size_t)b * NNq * 32;
  const unsigned short* klb = kl_ + (size_t)b * NNq * 32;
  const unsigned short* vb = vbf + (size_t)b * CC * NNq;
  float* attn = out + 8388608 + (size_t)b * NNq * NNq + (size_t)(tile * 16) * NNq;
  const int m0 = s2 * 1024;

  f32x4 acc[16];
#pragma unroll
  for (int ct = 0; ct < 16; ++ct) acc[ct] = f32x4{0.f, 0.f, 0.f, 0.f};

#pragma unroll 1
  for (int it = 0; it < 32; ++it) {
    const int mb = m0 + it * 32;
    const int cbase = (it & 1) * 32;
    // energies for two 16-m halves -> p -> LDS
#pragma unroll
    for (int hh = 0; hh < 2; ++hh) {
      size_t ko = (size_t)(mb + hh * 16 + l15) * 32 + l4 * 8;
      bf16x8 khf = *(const bf16x8*)(khb + ko);
      bf16x8 klf = *(const bf16x8*)(klb + ko);
      f32x4 e = {0.f, 0.f, 0.f, 0.f};
      e = MFMA16(qh, klf, e);
      e = MFMA16(qlo, khf, e);
      e = MFMA16(qh, khf, e);
#pragma unroll
      for (int j = 0; j < 4; ++j) {
        float p = exp2f(e[j] - crow[j]);
        int row = l4 * 4 + j;
        *(float*)(pb + swzb(row, (cbase + hh * 16 + l15) * 4)) = p;
      }
    }
    // PV B-fragment: lane = (n=l15, m=l4*8+i), read f32 + cvt bf16
    {
      int rb = l15 * 256, sw = (l15 & 7) << 4;
      int c0b = cbase * 4 + l4 * 32;
      f32x4 f0 = *(const f32x4*)(pb + rb + ((c0b) ^ sw));
      f32x4 f1 = *(const f32x4*)(pb + rb + ((c0b + 16) ^ sw));
      bf16x8 pfrag;
#pragma unroll
      for (int i = 0; i < 4; ++i) {
        pfrag[i] = f2bf(f0[i]);
        pfrag[i + 4] = f2bf(f1[i]);
      }
#pragma unroll
      for (int ct = 0; ct < 16; ++ct) {
        bf16x8 vf = *(const bf16x8*)(vb + (size_t)(ct * 16 + l15) * NNq + mb + l4 * 8);
        acc[ct] = MFMA16(vf, pfrag, acc[ct]);
      }
    }
    // every 64 m: coalesced attention store (4 rows x 256B per instruction)
    if (it & 1) {
      int ms = mb - 32;
#pragma unroll
      for (int s = 0; s < 4; ++s) {
        int row = s * 4 + l4;
        f32x4 pv = *(const f32x4*)(pb + swzb(row, l15 * 16));
        *(f32x4*)(attn + (size_t)row * NNq + ms + l15 * 4) = pv;
      }
    }
  }

  // partial PV store: part[(tg*4+s2)][c(256)][n16]
  float* pp = part + ((size_t)tg * 4 + s2) * 4096;
#pragma unroll
  for (int ct = 0; ct < 16; ++ct)
#pragma unroll
    for (int j = 0; j < 4; ++j)
      pp[(ct * 16 + l4 * 4 + j) * 16 + l15] = acc[ct][j];
}

// ---------------------------------------------------------------------------
// Kernel 4: reduce partials + epilogue (weighted = gamma*pv ; final = w + x)
// ---------------------------------------------------------------------------
__global__ __launch_bounds__(256) void reduce_kernel(
    const float* __restrict__ part, const float* __restrict__ x,
    const float* __restrict__ gamma, float* __restrict__ out)
{
  const int tg = blockIdx.x;            // b*256 + tile
  const int b = tg >> 8, tile = tg & 255;
  const float gm = gamma[0];
  const float* p0 = part + (size_t)tg * 4 * 4096;
#pragma unroll 1
  for (int i = 0; i < 16; ++i) {
    int idx = i * 256 + threadIdx.x;    // [0,4096) = c*16 + n16
    float s = p0[idx] + p0[4096 + idx] + p0[8192 + idx] + p0[12288 + idx];
    int c = idx >> 4, n16 = idx & 15;
    size_t go = ((size_t)b * CC + c) * NNq + tile * 16 + n16;
    float wv = gm * s;
    out[4194304 + go] = wv;
    out[go] = wv + x[go];
  }
}

extern "C" void kernel_launch(void* const* d_in, const int* in_sizes, int n_in,
                              void* d_out, int out_size, void* d_ws, size_t ws_size,
                              hipStream_t stream) {
  const float* x     = (const float*)d_in[0];
  const float* Wq    = (const float*)d_in[1];
  const float* bq    = (const float*)d_in[2];
  const float* Wk    = (const float*)d_in[3];
  const float* bk    = (const float*)d_in[4];
  const float* Wv    = (const float*)d_in[5];
  const float* bv    = (const float*)d_in[6];
  const float* gamma = (const float*)d_in[7];
  float* out = (float*)d_out;

  char* ws = (char*)d_ws;
  unsigned short* qh   = (unsigned short*)(ws);                    // 1 MB
  unsigned short* ql   = (unsigned short*)(ws + (1u << 20));       // 1 MB
  unsigned short* kh   = (unsigned short*)(ws + (2u << 20));       // 1 MB
  unsigned short* kl   = (unsigned short*)(ws + (3u << 20));       // 1 MB
  unsigned short* vbf  = (unsigned short*)(ws + (4u << 20));       // 8 MB
  float* ps            = (float*)(ws + (12u << 20));               // 512 KB
  float* Crow          = (float*)(ws + (12u << 20) + (512u << 10));// 64 KB
  float* part          = (float*)(ws + (13u << 20));               // 64 MB

  proj_kernel<<<256, 256, 0, stream>>>(x, Wq, bq, Wk, bk, Wv, bv, qh, ql, kh, kl, vbf);
  stats_kernel<<<2048, 256, 0, stream>>>(qh, ql, kh, kl, ps);
  merge_kernel<<<64, 256, 0, stream>>>(ps, Crow);
  attn_pv_kernel<<<1024, 256, 0, stream>>>(qh, ql, kh, kl, vbf, Crow, out, part);
  reduce_kernel<<<1024, 256, 0, stream>>>(part, x, gamma, out);
}

// Round 3
// 192.210 us; speedup vs baseline: 1.9607x; 1.9607x over previous
//
#include <hip/hip_runtime.h>
#include <stdint.h>

#define CC 256
#define NNq 4096

typedef float f32x4 __attribute__((ext_vector_type(4)));
typedef short bf16x8 __attribute__((ext_vector_type(8)));

#define MFMA16(a, b, c) __builtin_amdgcn_mfma_f32_16x16x32_bf16(a, b, c, 0, 0, 0)

static __device__ __forceinline__ short f2bf(float f) {
  unsigned u = __builtin_bit_cast(unsigned, f);
  u += 0x7fffu + ((u >> 16) & 1u);   // RNE
  return (short)(u >> 16);
}
static __device__ __forceinline__ float bf2f(short s) {
  return __builtin_bit_cast(float, ((unsigned)(unsigned short)s) << 16);
}

// barrier that does NOT drain vmcnt (prefetch + stores stay in flight);
// sched_barrier(0) fences compile-time motion across it (rule 18).
#define SBAR() do { \
  __builtin_amdgcn_sched_barrier(0); \
  asm volatile("s_waitcnt lgkmcnt(0)" ::: "memory"); \
  __builtin_amdgcn_s_barrier(); \
  __builtin_amdgcn_sched_barrier(0); \
} while (0)

// ---------------------------------------------------------------------------
// Kernel 1: projections.
//  - q,k: split hi/lo bf16, separate arrays [B][N][32]; q pre-scaled by log2e.
//  - v: bf16 pre-tiled as MFMA A-fragments: v5[b][m>>5][c][m&31]
//    -> PV fragment loads are 1KB fully contiguous.
// ---------------------------------------------------------------------------
#define XSTR 66

__global__ __launch_bounds__(256) void proj_kernel(
    const float* __restrict__ x,
    const float* __restrict__ Wq, const float* __restrict__ bq,
    const float* __restrict__ Wk, const float* __restrict__ bk,
    const float* __restrict__ Wv, const float* __restrict__ bv,
    unsigned short* __restrict__ qh_, unsigned short* __restrict__ ql_,
    unsigned short* __restrict__ kh_, unsigned short* __restrict__ kl_,
    unsigned short* __restrict__ v5)
{
  __shared__ float xs[256 * XSTR];
  const int t = threadIdx.x;
  const int b = blockIdx.x >> 6;
  const int n0 = (blockIdx.x & 63) << 6;
  const float L2E = 1.4426950408889634f;

  const float* xb = x + ((size_t)b * CC) * NNq + n0;
#pragma unroll
  for (int i = 0; i < 16; ++i) {
    int fi = i * 256 + t;
    int c = fi >> 4, nv = (fi & 15) << 2;
    float4 v4 = *(const float4*)(xb + (size_t)c * NNq + nv);
    float* d = &xs[c * XSTR + nv];
    d[0] = v4.x; d[1] = v4.y; d[2] = v4.z; d[3] = v4.w;
  }
  __syncthreads();

  const int w = t >> 6, l = t & 63;
  const int l15 = l & 15, l4 = l >> 4;

  // 20 row-tiles: 16 v + 2 q + 2 k ; wave w owns tiles w*5 .. w*5+4
  f32x4 acc[5][4];
#pragma unroll
  for (int r5 = 0; r5 < 5; ++r5) {
    int rt = w * 5 + r5;
    const float* bias; float bscale;
    if (rt < 16)      { bias = bv + rt * 16;        bscale = 1.f; }
    else if (rt < 18) { bias = bq + (rt - 16) * 16; bscale = L2E; }
    else              { bias = bk + (rt - 18) * 16; bscale = 1.f; }
#pragma unroll
    for (int j = 0; j < 4; ++j) {
      float bval = bias[l4 * 4 + j] * bscale;
#pragma unroll
      for (int nt = 0; nt < 4; ++nt) acc[r5][nt][j] = bval;
    }
  }

#pragma unroll 1
  for (int ks = 0; ks < 8; ++ks) {
    bf16x8 ah[5], al[5];
#pragma unroll
    for (int r5 = 0; r5 < 5; ++r5) {
      int rt = w * 5 + r5;
      const float* wrow; float wscale;
      if (rt < 16)      { wrow = Wv + (size_t)(rt * 16 + l15) * 256;        wscale = 1.f; }
      else if (rt < 18) { wrow = Wq + (size_t)((rt - 16) * 16 + l15) * 256; wscale = L2E; }
      else              { wrow = Wk + (size_t)((rt - 18) * 16 + l15) * 256; wscale = 1.f; }
      const float* src = wrow + ks * 32 + l4 * 8;
#pragma unroll
      for (int i = 0; i < 8; ++i) {
        float v = src[i] * wscale;
        short hh = f2bf(v);
        ah[r5][i] = hh;
        al[r5][i] = f2bf(v - bf2f(hh));
      }
    }
#pragma unroll
    for (int nt = 0; nt < 4; ++nt) {
      bf16x8 bh, bl;
#pragma unroll
      for (int i = 0; i < 8; ++i) {
        float v = xs[(ks * 32 + l4 * 8 + i) * XSTR + nt * 16 + l15];
        short hh = f2bf(v);
        bh[i] = hh;
        bl[i] = f2bf(v - bf2f(hh));
      }
#pragma unroll
      for (int r5 = 0; r5 < 5; ++r5) {
        acc[r5][nt] = MFMA16(ah[r5], bl, acc[r5][nt]);
        acc[r5][nt] = MFMA16(al[r5], bh, acc[r5][nt]);
        acc[r5][nt] = MFMA16(ah[r5], bh, acc[r5][nt]);
      }
    }
  }

#pragma unroll
  for (int r5 = 0; r5 < 5; ++r5) {
    int rt = w * 5 + r5;
#pragma unroll
    for (int nt = 0; nt < 4; ++nt) {
      int n = n0 + nt * 16 + l15;
#pragma unroll
      for (int j = 0; j < 4; ++j) {
        float v = acc[r5][nt][j];
        int sub = l4 * 4 + j;
        if (rt < 16) {
          int c = rt * 16 + sub;
          // v5[b][n>>5][c][n&31]
          size_t o = (((size_t)b * 128 + (n >> 5)) * 256 + c) * 32 + (n & 31);
          v5[o] = (unsigned short)f2bf(v);
        } else {
          short hh = f2bf(v);
          short lo = f2bf(v - bf2f(hh));
          unsigned short* dh = (rt < 18) ? qh_ : kh_;
          unsigned short* dl = (rt < 18) ? ql_ : kl_;
          int d = ((rt < 18) ? (rt - 16) : (rt - 18)) * 16 + sub;
          size_t o = ((size_t)b * NNq + n) * 32 + d;
          dh[o] = (unsigned short)hh;
          dl[o] = (unsigned short)lo;
        }
      }
    }
  }
}

// ---------------------------------------------------------------------------
// Kernel 2: fused softmax-stats + attention write + PV + epilogue.
// Block = 512 threads (8 waves) owns (b, 64 rows), all 4096 m. Grid 256 = 1/CU.
// Energy role: wave (g = 16-row group, h = 32-m half). PV role: wave = 32-c slice.
// Pass 1: row sums with fixed shift 64 (no barriers, reg-prefetched k).
// Pass 2: per 64-m chunk: energy -> attn f32 stores + p(bf16) -> swizzled LDS
//         -> barrier -> PV MFMA (v frags = contiguous 1KB global loads,
//         prefetched 1 chunk ahead) -> barrier. vmcnt never drained.
// ---------------------------------------------------------------------------
__global__ __launch_bounds__(512, 1) void attn_pv_kernel(
    const unsigned short* __restrict__ qh_, const unsigned short* __restrict__ ql_,
    const unsigned short* __restrict__ kh_, const unsigned short* __restrict__ kl_,
    const unsigned short* __restrict__ v5, const float* __restrict__ x,
    const float* __restrict__ gamma, float* __restrict__ out)
{
  __shared__ __align__(16) unsigned short p_lds[2][4096]; // [par][64 n][64 m] bf16, XOR-swz
  __shared__ float sums_lds[2][64];

  const int t = threadIdx.x, w = t >> 6, l = t & 63;
  const int l15 = l & 15, l4 = l >> 4;
  // XCD swizzle: 256 blocks -> 32 consecutive sb per XCD (each b spans 2 XCDs)
  const int sb = ((blockIdx.x & 7) << 5) | (blockIdx.x >> 3);
  const int b = sb >> 6;
  const int n0 = (sb & 63) << 6;
  const int g = w >> 1, h = w & 1;

  const size_t qbase = ((size_t)b * NNq + n0 + g * 16 + l15) * 32 + l4 * 8;
  const bf16x8 qh = *(const bf16x8*)(qh_ + qbase);
  const bf16x8 qlo = *(const bf16x8*)(ql_ + qbase);
  const unsigned short* khb = kh_ + (size_t)b * NNq * 32;
  const unsigned short* klb = kl_ + (size_t)b * NNq * 32;
  const unsigned short* vbb = v5 + (size_t)b * 1048576;
  float* attn = out + 8388608 + (size_t)b * NNq * NNq + (size_t)n0 * NNq;

  // ---------------- pass 1: row sums (log2 domain, fixed shift 64) ----------
  float sx[4] = {0.f, 0.f, 0.f, 0.f};
  {
    bf16x8 kch[2], kcl[2];
#pragma unroll
    for (int mt = 0; mt < 2; ++mt) {
      size_t ko = (size_t)(h * 32 + mt * 16 + l15) * 32 + l4 * 8;
      kch[mt] = *(const bf16x8*)(khb + ko);
      kcl[mt] = *(const bf16x8*)(klb + ko);
    }
#pragma unroll 1
    for (int c0 = 0; c0 < NNq; c0 += 64) {
      int nx = (c0 + 64) & (NNq - 1);
      bf16x8 knh[2], knl[2];
#pragma unroll
      for (int mt = 0; mt < 2; ++mt) {
        size_t ko = (size_t)(nx + h * 32 + mt * 16 + l15) * 32 + l4 * 8;
        knh[mt] = *(const bf16x8*)(khb + ko);
        knl[mt] = *(const bf16x8*)(klb + ko);
      }
#pragma unroll
      for (int mt = 0; mt < 2; ++mt) {
        f32x4 e = {0.f, 0.f, 0.f, 0.f};
        e = MFMA16(qh, kcl[mt], e);
        e = MFMA16(qlo, kch[mt], e);
        e = MFMA16(qh, kch[mt], e);
#pragma unroll
        for (int j = 0; j < 4; ++j) sx[j] += exp2f(e[j] - 64.0f);
      }
      kch[0] = knh[0]; kch[1] = knh[1];
      kcl[0] = knl[0]; kcl[1] = knl[1];
    }
  }
#pragma unroll
  for (int mask = 1; mask < 16; mask <<= 1)
#pragma unroll
    for (int j = 0; j < 4; ++j) sx[j] += __shfl_xor(sx[j], mask);
  if (l15 == 0) {
#pragma unroll
    for (int j = 0; j < 4; ++j) sums_lds[h][g * 16 + l4 * 4 + j] = sx[j];
  }
  __syncthreads();
  f32x4 crow;
#pragma unroll
  for (int j = 0; j < 4; ++j) {
    int r = g * 16 + l4 * 4 + j;
    crow[j] = 64.0f + log2f(sums_lds[0][r] + sums_lds[1][r]);
  }

  // ---------------- pass 2: attention + PV ----------------
  f32x4 acc[2][4];   // c = w*32+ct*16+l4*4+j ; n = n0+nt*16+l15
#pragma unroll
  for (int ct = 0; ct < 2; ++ct)
#pragma unroll
    for (int nt = 0; nt < 4; ++nt) acc[ct][nt] = f32x4{0.f, 0.f, 0.f, 0.f};

  bf16x8 kch[2], kcl[2], vc[2][2];
#pragma unroll
  for (int mt = 0; mt < 2; ++mt) {
    size_t ko = (size_t)(h * 32 + mt * 16 + l15) * 32 + l4 * 8;
    kch[mt] = *(const bf16x8*)(khb + ko);
    kcl[mt] = *(const bf16x8*)(klb + ko);
  }
#pragma unroll
  for (int ct = 0; ct < 2; ++ct)
#pragma unroll
    for (int mh = 0; mh < 2; ++mh) {
      size_t vo = ((size_t)mh * 256 + (w * 32 + ct * 16 + l15)) * 32 + l4 * 8;
      vc[ct][mh] = *(const bf16x8*)(vbb + vo);
    }

  int par = 0;
#pragma unroll 1
  for (int c0 = 0; c0 < NNq; c0 += 64, par ^= 1) {
    int nx = (c0 + 64) & (NNq - 1);
    // prefetch next chunk's k and v fragments (in flight across barriers)
    bf16x8 knh[2], knl[2], vn[2][2];
#pragma unroll
    for (int mt = 0; mt < 2; ++mt) {
      size_t ko = (size_t)(nx + h * 32 + mt * 16 + l15) * 32 + l4 * 8;
      knh[mt] = *(const bf16x8*)(khb + ko);
      knl[mt] = *(const bf16x8*)(klb + ko);
    }
#pragma unroll
    for (int ct = 0; ct < 2; ++ct)
#pragma unroll
      for (int mh = 0; mh < 2; ++mh) {
        size_t vo = (((size_t)nx >> 5) + mh) * 256 * 32 +
                    (size_t)(w * 32 + ct * 16 + l15) * 32 + l4 * 8;
        vn[ct][mh] = *(const bf16x8*)(vbb + vo);
      }

    // A: energy -> attention stores (f32) + p -> swizzled LDS (bf16)
    char* pl = (char*)p_lds[par];
#pragma unroll
    for (int mt = 0; mt < 2; ++mt) {
      f32x4 e = {0.f, 0.f, 0.f, 0.f};
      e = MFMA16(qh, kcl[mt], e);
      e = MFMA16(qlo, kch[mt], e);
      e = MFMA16(qh, kch[mt], e);
#pragma unroll
      for (int j = 0; j < 4; ++j) {
        float p = exp2f(e[j] - crow[j]);
        int nl = g * 16 + l4 * 4 + j;
        int ml = h * 32 + mt * 16 + l15;
        attn[(size_t)nl * NNq + c0 + ml] = p;
        int byteo = nl * 128 + ((ml * 2) ^ ((nl & 7) << 4));
        *(unsigned short*)(pl + byteo) = (unsigned short)f2bf(p);
      }
    }
    SBAR();
    // B: PV — A-operand = v frags (prefetched), B-operand = p frags from LDS
#pragma unroll
    for (int mh = 0; mh < 2; ++mh) {
      bf16x8 pf0, pf1, pf2, pf3;
      {
        int mb = (mh * 32 + l4 * 8) * 2;
        int nl0 = l15,      o0 = nl0 * 128 + (mb ^ ((nl0 & 7) << 4));
        int nl1 = 16 + l15, o1 = nl1 * 128 + (mb ^ ((nl1 & 7) << 4));
        int nl2 = 32 + l15, o2 = nl2 * 128 + (mb ^ ((nl2 & 7) << 4));
        int nl3 = 48 + l15, o3 = nl3 * 128 + (mb ^ ((nl3 & 7) << 4));
        pf0 = *(const bf16x8*)(pl + o0);
        pf1 = *(const bf16x8*)(pl + o1);
        pf2 = *(const bf16x8*)(pl + o2);
        pf3 = *(const bf16x8*)(pl + o3);
      }
#pragma unroll
      for (int ct = 0; ct < 2; ++ct) {
        acc[ct][0] = MFMA16(vc[ct][mh], pf0, acc[ct][0]);
        acc[ct][1] = MFMA16(vc[ct][mh], pf1, acc[ct][1]);
        acc[ct][2] = MFMA16(vc[ct][mh], pf2, acc[ct][2]);
        acc[ct][3] = MFMA16(vc[ct][mh], pf3, acc[ct][3]);
      }
    }
    SBAR();
    // rotate prefetch
    kch[0] = knh[0]; kch[1] = knh[1];
    kcl[0] = knl[0]; kcl[1] = knl[1];
#pragma unroll
    for (int ct = 0; ct < 2; ++ct)
#pragma unroll
      for (int mh = 0; mh < 2; ++mh) vc[ct][mh] = vn[ct][mh];
  }

  // epilogue: weighted = gamma*pv ; final = weighted + x
  float gm = gamma[0];
#pragma unroll
  for (int ct = 0; ct < 2; ++ct) {
#pragma unroll
    for (int nt = 0; nt < 4; ++nt) {
#pragma unroll
      for (int j = 0; j < 4; ++j) {
        int c = w * 32 + ct * 16 + l4 * 4 + j;
        int n = n0 + nt * 16 + l15;
        size_t go = ((size_t)b * CC + c) * NNq + n;
        float o = acc[ct][nt][j] * gm;
        out[4194304 + go] = o;
        out[go] = o + x[go];
      }
    }
  }
}

extern "C" void kernel_launch(void* const* d_in, const int* in_sizes, int n_in,
                              void* d_out, int out_size, void* d_ws, size_t ws_size,
                              hipStream_t stream) {
  const float* x     = (const float*)d_in[0];
  const float* Wq    = (const float*)d_in[1];
  const float* bq    = (const float*)d_in[2];
  const float* Wk    = (const float*)d_in[3];
  const float* bk    = (const float*)d_in[4];
  const float* Wv    = (const float*)d_in[5];
  const float* bv    = (const float*)d_in[6];
  const float* gamma = (const float*)d_in[7];
  float* out = (float*)d_out;

  char* ws = (char*)d_ws;
  unsigned short* qh   = (unsigned short*)(ws);                    // 1 MB
  unsigned short* ql   = (unsigned short*)(ws + (1u << 20));       // 1 MB
  unsigned short* kh   = (unsigned short*)(ws + (2u << 20));       // 1 MB
  unsigned short* kl   = (unsigned short*)(ws + (3u << 20));       // 1 MB
  unsigned short* v5   = (unsigned short*)(ws + (4u << 20));       // 8 MB

  proj_kernel<<<256, 256, 0, stream>>>(x, Wq, bq, Wk, bk, Wv, bv, qh, ql, kh, kl, v5);
  attn_pv_kernel<<<256, 512, 0, stream>>>(qh, ql, kh, kl, v5, x, gamma, out);
}